// Round 1
// 858.845 us; speedup vs baseline: 1.0162x; 1.0162x over previous
//
#include <hip/hip_runtime.h>
#include <math.h>

#define TOPK 7
// dims (fixed by problem): L=S=2048, B=8, D=1024, H=16, E=64

typedef __attribute__((ext_vector_type(8))) short bf16x8;
typedef __attribute__((ext_vector_type(4))) float f32x4;

// ---------------------------------------------------------------------------
// async global->LDS, 16B per lane (wave-uniform LDS base + lane*16)
// ---------------------------------------------------------------------------
__device__ __forceinline__ void glds16(const ushort* g, ushort* l)
{
    __builtin_amdgcn_global_load_lds(
        (const __attribute__((address_space(1))) void*)g,
        (__attribute__((address_space(3))) void*)l, 16, 0, 0);
}

// ---------------------------------------------------------------------------
// fp32 -> (hi,lo) bf16 split, RN-even via bit ops. n4 = n/4.
// ---------------------------------------------------------------------------
__device__ __forceinline__ void split1(float x, ushort& h, ushort& lo)
{
    union U { float f; unsigned u; };
    U a; a.f = x;
    unsigned r = (a.u + 0x7FFFu + ((a.u >> 16) & 1u)) >> 16;
    h = (ushort)r;
    U b; b.u = r << 16;
    U d; d.f = x - b.f;
    unsigned r2 = (d.u + 0x7FFFu + ((d.u >> 16) & 1u)) >> 16;
    lo = (ushort)r2;
}

__global__ __launch_bounds__(256)
void split_f32(const float* __restrict__ x, ushort* __restrict__ hi,
               ushort* __restrict__ lo, int n4)
{
    for (int i = blockIdx.x * 256 + threadIdx.x; i < n4; i += gridDim.x * 256) {
        float4 v = ((const float4*)x)[i];
        ushort4 h, lw;
        split1(v.x, h.x, lw.x);
        split1(v.y, h.y, lw.y);
        split1(v.z, h.z, lw.z);
        split1(v.w, h.w, lw.w);
        ((ushort4*)hi)[i] = h;
        ((ushort4*)lo)[i] = lw;
    }
}

// ---------------------------------------------------------------------------
// split-bf16 NT GEMM: C[M,1024] = A[M,1024]*B[1024,1024]^T + bias
// A,B given as (hi,lo) bf16 pairs. C fp32.
// 128x128 tile, BK=32, 256 thr (4 waves, each 64x64 = 4x4 frags of 16x16).
// 3 MFMAs per frag-pair: Ah*Bh + Ah*Bl + Al*Bh  (error ~2^-17 rel).
// XCD-aware swizzle (T1): blocks sharing an A-panel (same by, all 8 bx)
// land on the SAME XCD so the panel streams from HBM once; B (4MB hi+lo)
// stays resident in each XCD's L2.
// ---------------------------------------------------------------------------
__global__ __launch_bounds__(256)
void gemm_split(const ushort* __restrict__ Ah, const ushort* __restrict__ Al,
                const ushort* __restrict__ Bh, const ushort* __restrict__ Bl,
                const float* __restrict__ bias, float* __restrict__ C)
{
    __shared__ ushort lds[16384];   // 4 tiles x 4096 ushort (8KB) = 32KB
    const int tid = threadIdx.x;
    const int w = tid >> 6, l = tid & 63;

    // T1 swizzle: ord%8 == XCD (round-robin dispatch); give each XCD a
    // contiguous chunk of logical blocks. nwg divisible by 8 -> bijective.
    const int ord = blockIdx.y * gridDim.x + blockIdx.x;
    const int cpx = (gridDim.x * gridDim.y) >> 3;
    const int swz = (ord & 7) * cpx + (ord >> 3);
    const int bx = swz & 7;          // gridDim.x == 8 (N tiles)
    const int by = swz >> 3;         // M tile

    const int wm = w >> 1, wn = w & 1;
    const int lr = l & 15, kgr = l >> 4;

    size_t aoff[2], boff[2];
    int loff[2];
#pragma unroll
    for (int t = 0; t < 2; ++t) {
        int idx8 = w * 2 + t;              // 0..7
        int kg = idx8 >> 1;                // 0..3
        int r  = (idx8 & 1) * 64 + l;      // 0..127
        aoff[t] = (size_t)(by * 128 + r) * 1024 + kg * 8;
        boff[t] = (size_t)(bx * 128 + r) * 1024 + kg * 8;
        loff[t] = idx8 * 512;              // ushort units (1KB per wave-inst)
    }

    f32x4 acc[4][4];
#pragma unroll
    for (int i = 0; i < 4; ++i)
#pragma unroll
        for (int j = 0; j < 4; ++j) acc[i][j] = (f32x4){0.f, 0.f, 0.f, 0.f};

    for (int k0 = 0; k0 < 1024; k0 += 32) {
        __syncthreads();   // previous iter's frag reads done before overwrite
#pragma unroll
        for (int t = 0; t < 2; ++t) {
            glds16(Ah + aoff[t] + k0, &lds[0     + loff[t]]);
            glds16(Al + aoff[t] + k0, &lds[4096  + loff[t]]);
            glds16(Bh + boff[t] + k0, &lds[8192  + loff[t]]);
            glds16(Bl + boff[t] + k0, &lds[12288 + loff[t]]);
        }
        __syncthreads();   // vmcnt drained by compiler before barrier

        bf16x8 fah[4], fal[4], fbh[4], fbl[4];
#pragma unroll
        for (int i = 0; i < 4; ++i) {
            int ra = wm * 64 + i * 16 + lr;
            int rb = wn * 64 + i * 16 + lr;
            fah[i] = *(const bf16x8*)&lds[        kgr * 1024 + ra * 8];
            fal[i] = *(const bf16x8*)&lds[4096  + kgr * 1024 + ra * 8];
            fbh[i] = *(const bf16x8*)&lds[8192  + kgr * 1024 + rb * 8];
            fbl[i] = *(const bf16x8*)&lds[12288 + kgr * 1024 + rb * 8];
        }
#pragma unroll
        for (int i = 0; i < 4; ++i)
#pragma unroll
            for (int j = 0; j < 4; ++j)
                acc[i][j] = __builtin_amdgcn_mfma_f32_16x16x32_bf16(fah[i], fbh[j], acc[i][j], 0, 0, 0);
#pragma unroll
        for (int i = 0; i < 4; ++i)
#pragma unroll
            for (int j = 0; j < 4; ++j)
                acc[i][j] = __builtin_amdgcn_mfma_f32_16x16x32_bf16(fah[i], fbl[j], acc[i][j], 0, 0, 0);
#pragma unroll
        for (int i = 0; i < 4; ++i)
#pragma unroll
            for (int j = 0; j < 4; ++j)
                acc[i][j] = __builtin_amdgcn_mfma_f32_16x16x32_bf16(fal[i], fbh[j], acc[i][j], 0, 0, 0);
    }

    // epilogue: C/D layout col = lane&15, row = (lane>>4)*4 + reg  [m89-verified]
#pragma unroll
    for (int j = 0; j < 4; ++j) {
        int col = bx * 128 + wn * 64 + j * 16 + lr;
        float bb = bias[col];
#pragma unroll
        for (int i = 0; i < 4; ++i) {
            int row0 = by * 128 + wm * 64 + i * 16 + kgr * 4;
#pragma unroll
            for (int reg = 0; reg < 4; ++reg)
                C[(size_t)(row0 + reg) * 1024 + col] = acc[i][j][reg] + bb;
        }
    }
}

// ---------------------------------------------------------------------------
// transpose (t,b,d) -> [bh][e][t]   (for coalesced FFT row loads)
// ---------------------------------------------------------------------------
__global__ __launch_bounds__(256)
void transpose_bhet(const float* __restrict__ src, float* __restrict__ dst)
{
    __shared__ float tile[64][129];
    const int tid = threadIdx.x;
    const int bh = blockIdx.x;
    const int b = bh >> 4, h = bh & 15;
    const int t0 = blockIdx.y * 128;
    const float* sp = src + (size_t)(t0 * 8 + b) * 1024 + h * 64;
#pragma unroll
    for (int i = 0; i < 8; ++i) {
        int idx = i * 256 + tid;
        int t = idx >> 4;
        int e4 = (idx & 15) * 4;
        float4 v = *(const float4*)(sp + (size_t)t * 8192 + e4);
        tile[e4 + 0][t] = v.x; tile[e4 + 1][t] = v.y; tile[e4 + 2][t] = v.z; tile[e4 + 3][t] = v.w;
    }
    __syncthreads();
    float* dp = dst + (size_t)bh * 64 * 2048 + t0;
#pragma unroll
    for (int i = 0; i < 8; ++i) {
        int idx = i * 256 + tid;
        int e = idx >> 5;
        int t4 = (idx & 31) * 4;
        float4 o;
        o.x = tile[e][t4]; o.y = tile[e][t4 + 1]; o.z = tile[e][t4 + 2]; o.w = tile[e][t4 + 3];
        *(float4*)(dp + (size_t)e * 2048 + t4) = o;
    }
}

// ---------------------------------------------------------------------------
__device__ __forceinline__ float2 cadd(float2 a, float2 b){ return make_float2(a.x+b.x, a.y+b.y); }
__device__ __forceinline__ float2 csub(float2 a, float2 b){ return make_float2(a.x-b.x, a.y-b.y); }
__device__ __forceinline__ float2 cmul(float2 a, float2 b){ return make_float2(a.x*b.x - a.y*b.y, a.x*b.y + a.y*b.x); }

// ---------------------------------------------------------------------------
// corr_fwd: grid (128 bh, 8 eg). FFT 8 packed (Q,K) rows, accumulate partial
// S[f] = sum_e Qf*conj(Kf) in registers, write to Spart[bh][eg][1025].
// Twiddle LUT: exp(-i*pi*ps/1024), ps in [0,1024) covers ALL stages -- built
// once per block (4 sincospif/thread) instead of per-butterfly (352/thread).
// Bitwise-identical numerics (same sincospif values).
// ---------------------------------------------------------------------------
__global__ __launch_bounds__(256)
void corr_fwd(const float* __restrict__ Qa, const float* __restrict__ Ka,
              float2* __restrict__ Spart)
{
    __shared__ float2 za[2048];
    __shared__ float2 zb[2048];
    __shared__ float2 tw[1024];
    const int tid = threadIdx.x;
    const int bh = blockIdx.x;
    const int eg = blockIdx.y;

#pragma unroll
    for (int r = 0; r < 4; ++r) {
        int u = tid + 256 * r;
        float sn, cs;
        sincospif((float)u * (1.0f / 1024.0f), &sn, &cs);
        tw[u] = make_float2(cs, -sn);
    }
    // visibility guaranteed by the __syncthreads after the first za fill

    float2 sacc[4];
#pragma unroll
    for (int r = 0; r < 4; ++r) sacc[r] = make_float2(0.f, 0.f);
    float2 sacc1024 = make_float2(0.f, 0.f);

    const float* q0 = Qa + ((size_t)bh * 64 + eg * 8) * 2048;
    const float* k0 = Ka + ((size_t)bh * 64 + eg * 8) * 2048;

    for (int e = 0; e < 8; ++e) {
        const float* qr = q0 + (size_t)e * 2048;
        const float* kr = k0 + (size_t)e * 2048;
        for (int t = tid; t < 2048; t += 256)
            za[t] = make_float2(qr[t], kr[t]);
        __syncthreads();
        float2* x = za; float2* y = zb;
#pragma unroll 1
        for (int st = 0; st < 11; ++st) {
            const int s = 1 << st;
#pragma unroll
            for (int ui = 0; ui < 4; ++ui) {
                int u = ui * 256 + tid;
                int q = u & (s - 1);
                int ps = u - q;
                float2 a  = x[u];
                float2 bb = x[u + 1024];
                float2 wv = tw[ps];
                int i1 = 2 * ps + q;
                y[i1]     = cadd(a, bb);
                y[i1 + s] = cmul(csub(a, bb), wv);
            }
            __syncthreads();
            float2* tsw = x; x = y; y = tsw;
        }
#pragma unroll
        for (int r = 0; r < 4; ++r) {
            int f = tid + 256 * r;
            float2 A  = x[f];
            float2 Bc = x[(2048 - f) & 2047];
            float Ur = A.x + Bc.x, Ui = A.y - Bc.y;
            float Vr = A.x - Bc.x, Vi = -A.y - Bc.y;
            sacc[r].x += 0.25f * (-(Ur * Vi + Ui * Vr));
            sacc[r].y += 0.25f * ( Ur * Vr - Ui * Vi );
        }
        if (tid == 0) {
            float2 A = x[1024];
            float Ur = 2.f * A.x;
            float Vi = -2.f * A.y;
            sacc1024.x += 0.25f * (-(Ur * Vi));
            sacc1024.y += 0.25f * 0.f;
        }
        __syncthreads();
    }
    float2* sp = Spart + ((size_t)bh * 8 + eg) * 1025;
#pragma unroll
    for (int r = 0; r < 4; ++r) sp[tid + 256 * r] = sacc[r];
    if (tid == 0) sp[1024] = sacc1024;
}

// ---------------------------------------------------------------------------
// corr_inv_topk: sum 8 partials, inverse FFT (conj trick), top-7 + softmax.
// Same twiddle-LUT treatment as corr_fwd.
// ---------------------------------------------------------------------------
__global__ __launch_bounds__(256)
void corr_inv_topk(const float2* __restrict__ Spart,
                   int* __restrict__ taus, float* __restrict__ wout)
{
    __shared__ float2 za[2048];
    __shared__ float2 zb[2048];
    __shared__ float2 tw[1024];
    __shared__ float2 Sh[1025];
    __shared__ float  redv[256];
    __shared__ int    redi[256];
    __shared__ float  sc[TOPK];
    __shared__ int    si[TOPK];

    const int tid = threadIdx.x;
    const int bh = blockIdx.x;

#pragma unroll
    for (int r = 0; r < 4; ++r) {
        int u = tid + 256 * r;
        float sn, cs;
        sincospif((float)u * (1.0f / 1024.0f), &sn, &cs);
        tw[u] = make_float2(cs, -sn);
    }

    const float2* sp0 = Spart + (size_t)bh * 8 * 1025;
    for (int f = tid; f < 1025; f += 256) {
        float2 s = make_float2(0.f, 0.f);
#pragma unroll
        for (int g = 0; g < 8; ++g) {
            float2 v = sp0[(size_t)g * 1025 + f];
            s.x += v.x; s.y += v.y;
        }
        Sh[f] = s;
    }
    __syncthreads();
    for (int f = tid; f < 2048; f += 256) {
        float2 v = (f <= 1024) ? make_float2(Sh[f].x, -Sh[f].y) : Sh[2048 - f];
        za[f] = v;
    }
    __syncthreads();
    float2* xi = za; float2* yi = zb;
#pragma unroll 1
    for (int st = 0; st < 11; ++st) {
        const int s = 1 << st;
#pragma unroll
        for (int ui = 0; ui < 4; ++ui) {
            int u = ui * 256 + tid;
            int q = u & (s - 1);
            int ps = u - q;
            float2 a  = xi[u];
            float2 bb = xi[u + 1024];
            float2 wv = tw[ps];
            int i1 = 2 * ps + q;
            yi[i1]     = cadd(a, bb);
            yi[i1 + s] = cmul(csub(a, bb), wv);
        }
        __syncthreads();
        float2* tsw = xi; xi = yi; yi = tsw;
    }

    for (int k = 0; k < TOPK; ++k) {
        float bvv = -INFINITY; int bii = 0;
        for (int t = tid; t < 2048; t += 256) {
            float v = xi[t].x;
            if (v > bvv) { bvv = v; bii = t; }
        }
        redv[tid] = bvv; redi[tid] = bii;
        __syncthreads();
        for (int off = 128; off > 0; off >>= 1) {
            if (tid < off) {
                float ov = redv[tid + off]; int oi = redi[tid + off];
                if (ov > redv[tid] || (ov == redv[tid] && oi < redi[tid])) { redv[tid] = ov; redi[tid] = oi; }
            }
            __syncthreads();
        }
        if (tid == 0) { sc[k] = redv[0]; si[k] = redi[0]; xi[redi[0]].x = -INFINITY; }
        __syncthreads();
    }
    if (tid == 0) {
        const float scale = 1.0f / (2048.0f * 64.0f);
        float m = sc[0] * scale;
        float ex[TOPK]; float ssum = 0.f;
        for (int k = 0; k < TOPK; ++k) { ex[k] = expf(sc[k] * scale - m); ssum += ex[k]; }
        for (int k = 0; k < TOPK; ++k) {
            taus[bh * TOPK + k] = si[k];
            wout[bh * TOPK + k] = ex[k] / ssum;
        }
    }
}

// ---------------------------------------------------------------------------
// agg = (1/7) * sum_k w[bh][k] * V[(t+tau_k)%L, b, :]; emits (hi,lo) bf16
// directly (feeds the split-GEMM output projection).
// ---------------------------------------------------------------------------
__global__ __launch_bounds__(256)
void agg_gather(const float* __restrict__ Vp, const int* __restrict__ taus,
                const float* __restrict__ w, ushort* __restrict__ ah,
                ushort* __restrict__ al)
{
    const int tid = threadIdx.x;
    const int bh = blockIdx.x;
    const int b = bh >> 4, h = bh & 15;
    const int t0 = blockIdx.y * 256;
    __shared__ int   stau[TOPK];
    __shared__ float sw[TOPK];
    if (tid < TOPK) { stau[tid] = taus[bh * TOPK + tid]; sw[tid] = w[bh * TOPK + tid] * (1.0f / TOPK); }
    __syncthreads();
    const float* vb = Vp + (size_t)b * 1024 + h * 64;
    ushort* ahb = ah + (size_t)b * 1024 + h * 64;
    ushort* alb = al + (size_t)b * 1024 + h * 64;
#pragma unroll
    for (int i = 0; i < 16; ++i) {
        int idx = i * 256 + tid;
        int t  = t0 + (idx >> 4);
        int e4 = (idx & 15) * 4;
        float a0 = 0.f, a1 = 0.f, a2 = 0.f, a3 = 0.f;
#pragma unroll
        for (int k = 0; k < TOPK; ++k) {
            int ts = (t + stau[k]) & 2047;
            float4 v = *(const float4*)(vb + (size_t)ts * 8192 + e4);
            a0 = fmaf(sw[k], v.x, a0); a1 = fmaf(sw[k], v.y, a1);
            a2 = fmaf(sw[k], v.z, a2); a3 = fmaf(sw[k], v.w, a3);
        }
        ushort4 hh, ll;
        split1(a0, hh.x, ll.x); split1(a1, hh.y, ll.y);
        split1(a2, hh.z, ll.z); split1(a3, hh.w, ll.w);
        *(ushort4*)(ahb + (size_t)t * 8192 + e4) = hh;
        *(ushort4*)(alb + (size_t)t * 8192 + e4) = ll;
    }
}

// ---------------------------------------------------------------------------
extern "C" void kernel_launch(void* const* d_in, const int* in_sizes, int n_in,
                              void* d_out, int out_size, void* d_ws, size_t ws_size,
                              hipStream_t stream)
{
    (void)in_sizes; (void)n_in; (void)out_size; (void)ws_size;
    const float* query = (const float*)d_in[0];
    const float* key   = (const float*)d_in[1];
    const float* value = (const float*)d_in[2];
    const float* Wq = (const float*)d_in[3];
    const float* bq = (const float*)d_in[4];
    const float* Wk = (const float*)d_in[5];
    const float* bk = (const float*)d_in[6];
    const float* Wv = (const float*)d_in[7];
    const float* bv = (const float*)d_in[8];
    const float* Wo = (const float*)d_in[9];
    const float* bo = (const float*)d_in[10];
    float* out = (float*)d_out;

    const size_t NEL  = (size_t)16777216;   // 16384*1024
    const size_t HEL  = NEL / 2;            // value half
    const size_t WEL  = (size_t)1048576;    // 1024*1024
    const size_t SLOTB = (size_t)64 * 1024 * 1024;

    char* ws = (char*)d_ws;
    float*  s1 = (float*)ws;                 // fp32 proj outputs (Qp/Kp/Vp)
    char*   s2 = ws + SLOTB;                 // X(q) -> Qa -> agg hi/lo
    char*   s3 = ws + 2 * SLOTB;             // Wq -> X(k) -> Ka -> Wo
    int*    dtaus = (int*)(ws + 3 * SLOTB);
    float*  dw    = (float*)(dtaus + 128 * TOPK);

    dim3 blk(256);
    dim3 gemm_full(8, 128), gemm_half(8, 64);
    dim3 tr_grid(128, 16);

    // 1. Wq split -> s3
    split_f32<<<1024, blk, 0, stream>>>(Wq, (ushort*)s3, (ushort*)s3 + WEL, (int)(WEL / 4));
    // 2. query split -> s2
    split_f32<<<2048, blk, 0, stream>>>(query, (ushort*)s2, (ushort*)s2 + NEL, (int)(NEL / 4));
    // 3. Q projection -> s1
    gemm_split<<<gemm_full, blk, 0, stream>>>((ushort*)s2, (ushort*)s2 + NEL,
                                              (ushort*)s3, (ushort*)s3 + WEL, bq, s1);
    // 4. transpose -> Qa (s2, fp32)
    transpose_bhet<<<tr_grid, blk, 0, stream>>>(s1, (float*)s2);
    // 5. Wk split -> d_out[0:4MB)
    ushort* wkh = (ushort*)d_out;
    split_f32<<<1024, blk, 0, stream>>>(Wk, wkh, wkh + WEL, (int)(WEL / 4));
    // 6. key split -> s3
    split_f32<<<2048, blk, 0, stream>>>(key, (ushort*)s3, (ushort*)s3 + NEL, (int)(NEL / 4));
    // 7. K projection -> s1
    gemm_split<<<gemm_full, blk, 0, stream>>>((ushort*)s3, (ushort*)s3 + NEL,
                                              wkh, wkh + WEL, bk, s1);
    // 8. transpose -> Ka (s3, fp32)
    transpose_bhet<<<tr_grid, blk, 0, stream>>>(s1, (float*)s3);
    // 9. Wv split -> d_out + 32MB
    ushort* wvh = (ushort*)((char*)d_out + (size_t)32 * 1024 * 1024);
    split_f32<<<1024, blk, 0, stream>>>(Wv, wvh, wvh + WEL, (int)(WEL / 4));
    // 10-13. V projection in two M-halves (keeps value split within d_out[0:32MB))
    ushort* vsp = (ushort*)d_out;
    for (int hhalf = 0; hhalf < 2; ++hhalf) {
        split_f32<<<2048, blk, 0, stream>>>(value + hhalf * HEL, vsp, vsp + HEL, (int)(HEL / 4));
        gemm_split<<<gemm_half, blk, 0, stream>>>(vsp, vsp + HEL, wvh, wvh + WEL,
                                                  bv, s1 + hhalf * HEL);
    }
    // 14. correlation forward (Qa=s2, Ka=s3) -> Spart in d_out
    float2* Spart = (float2*)d_out;
    corr_fwd<<<dim3(128, 8), blk, 0, stream>>>((const float*)s2, (const float*)s3, Spart);
    // 15. inverse + top-k + softmax
    corr_inv_topk<<<dim3(128), blk, 0, stream>>>(Spart, dtaus, dw);
    // 16. delayed-V aggregation -> (hi,lo) in s2
    agg_gather<<<dim3(128, 8), blk, 0, stream>>>(s1, dtaus, dw,
                                                 (ushort*)s2, (ushort*)s2 + NEL);
    // 17. Wo split -> s3
    split_f32<<<1024, blk, 0, stream>>>(Wo, (ushort*)s3, (ushort*)s3 + WEL, (int)(WEL / 4));
    // 18. output projection -> d_out
    gemm_split<<<gemm_full, blk, 0, stream>>>((ushort*)s2, (ushort*)s2 + NEL,
                                              (ushort*)s3, (ushort*)s3 + WEL, bo, out);
}